// Round 1
// baseline (551.451 us; speedup 1.0000x reference)
//
#include <hip/hip_runtime.h>

#define DIM   2048
#define NEXP  64
#define NTOK  32768
#define DC    128   // d-chunk staged in LDS (32 KB)
#define TPW   8     // tokens per wave (register-blocked)
#define TB    32    // tokens per block (4 waves * TPW)

__global__ void zero_denom_kernel(float* __restrict__ denom) {
    denom[threadIdx.x] = 0.0f;
}

// Lane = expert (E == wavefront size == 64). Each wave computes logits for
// TPW tokens; W chunk lives in LDS (reads are 2-way bank aliased -> free).
__global__ __launch_bounds__(256, 4)
void gate_kernel(const float* __restrict__ x, const float* __restrict__ w,
                 const float* __restrict__ b, float* __restrict__ out,
                 float* __restrict__ denom)
{
    __shared__ float wlds[DC * NEXP];   // 32 KB
    __shared__ float dlds[NEXP];

    const int tid  = threadIdx.x;
    const int lane = tid & 63;
    const int wv   = tid >> 6;
    const int tok0 = blockIdx.x * TB + wv * TPW;

    if (tid < NEXP) dlds[tid] = 0.0f;

    float acc[TPW], cmp[TPW];
#pragma unroll
    for (int j = 0; j < TPW; ++j) { acc[j] = 0.0f; cmp[j] = 0.0f; }

    for (int c = 0; c < DIM; c += DC) {
        __syncthreads();
        {
            // cooperative load of w[c..c+DC)[*]: DC*NEXP floats, coalesced float4
            const float4* wsrc = (const float4*)(w + (size_t)c * NEXP);
            float4* wdst = (float4*)wlds;
#pragma unroll
            for (int i = 0; i < (DC * NEXP) / (256 * 4); ++i)
                wdst[i * 256 + tid] = wsrc[i * 256 + tid];
        }
        __syncthreads();

        float ca[TPW];
#pragma unroll
        for (int j = 0; j < TPW; ++j) ca[j] = 0.0f;

        for (int d4 = 0; d4 < DC; d4 += 4) {
            float4 xv[TPW];
#pragma unroll
            for (int j = 0; j < TPW; ++j)
                xv[j] = *(const float4*)(x + (size_t)(tok0 + j) * DIM + c + d4);
#pragma unroll
            for (int dd = 0; dd < 4; ++dd) {
                const float wval = wlds[(d4 + dd) * NEXP + lane];
#pragma unroll
                for (int j = 0; j < TPW; ++j) {
                    const float xs = ((const float*)&xv[j])[dd];
                    ca[j] = fmaf(xs, wval, ca[j]);
                }
            }
        }
        // Kahan-compensated fold of the chunk partial into the master sum
        // (keeps logit error ~5e-7 so argmax matches the np fp32 reference)
#pragma unroll
        for (int j = 0; j < TPW; ++j) {
            float y = ca[j] - cmp[j];
            float t = acc[j] + y;
            cmp[j] = (t - acc[j]) - y;
            acc[j] = t;
        }
    }

    const float bias = b[lane];

#pragma unroll
    for (int j = 0; j < TPW; ++j) {
        const float v = acc[j] + bias;

        // wave argmax (value, FIRST index on ties — matches jnp.argmax)
        float m = v; int mi = lane;
#pragma unroll
        for (int off = 32; off > 0; off >>= 1) {
            float om = __shfl_xor(m, off);
            int   oi = __shfl_xor(mi, off);
            if (om > m || (om == m && oi < mi)) { m = om; mi = oi; }
        }
        // softmax denominator; top-1 gate value = exp(m - m)/s = 1/s
        float s = __expf(v - m);
#pragma unroll
        for (int off = 32; off > 0; off >>= 1)
            s += __shfl_xor(s, off);
        const float g = 1.0f / s;

        const int t = tok0 + j;
        out[(size_t)t * NEXP + lane] = (lane == mi) ? g : 0.0f;
        if (lane == mi) atomicAdd(&dlds[mi], g);
    }

    __syncthreads();
    if (tid < NEXP) atomicAdd(&denom[tid], dlds[tid]);
}

// out[n,e] *= capacity / (denom[e] + eps); zeros stay zero (branch-free).
__global__ __launch_bounds__(256)
void scale_kernel(float* __restrict__ out, const float* __restrict__ denom)
{
    __shared__ float sc[NEXP];
    if (threadIdx.x < NEXP)
        sc[threadIdx.x] = (float)NTOK / (denom[threadIdx.x] + 1e-6f);
    __syncthreads();

    const size_t i = (size_t)blockIdx.x * blockDim.x + threadIdx.x; // float4 idx
    float4 v = ((const float4*)out)[i];
    const int e0 = (int)((i * 4) & (NEXP - 1));
    v.x *= sc[e0]; v.y *= sc[e0 + 1]; v.z *= sc[e0 + 2]; v.w *= sc[e0 + 3];
    ((float4*)out)[i] = v;
}

extern "C" void kernel_launch(void* const* d_in, const int* in_sizes, int n_in,
                              void* d_out, int out_size, void* d_ws, size_t ws_size,
                              hipStream_t stream) {
    const float* x = (const float*)d_in[0];
    const float* w = (const float*)d_in[1];
    const float* b = (const float*)d_in[2];
    float* out   = (float*)d_out;
    float* denom = (float*)d_ws;   // 64 floats

    zero_denom_kernel<<<1, NEXP, 0, stream>>>(denom);
    gate_kernel<<<NTOK / TB, 256, 0, stream>>>(x, w, b, out, denom);
    scale_kernel<<<(NTOK * NEXP / 4) / 256, 256, 0, stream>>>(out, denom);
}

// Round 2
// 254.577 us; speedup vs baseline: 2.1661x; 2.1661x over previous
//
#include <hip/hip_runtime.h>

#define DIM   2048
#define NEXP  64
#define NTOK  32768
#define DC    64                    // d-chunk per stage
#define NC    (DIM / DC)            // 32 chunks
#define TPW   16                    // tokens per wave
#define NWAVE 4
#define TB    (TPW * NWAVE)         // 64 tokens per block
#define NBLK  (NTOK / TB)           // 512 blocks = exactly 2/CU
#define WOFF  0
#define XOFF  (DC * NEXP)           // 4096 floats
#define BUFF  (DC * NEXP + TB * DC) // 8192 floats per buffer (32 KB)

typedef __attribute__((address_space(1))) const void gvoid_t;
typedef __attribute__((address_space(3))) void lvoid_t;
// async global->LDS, 16B per lane; LDS dest is wave-uniform base + lane*16 (linear)
#define GLDS16(g, l) __builtin_amdgcn_global_load_lds((gvoid_t*)(g), (lvoid_t*)(l), 16, 0, 0)

__global__ void zero_denom_kernel(float* __restrict__ denom) {
    denom[threadIdx.x] = 0.0f;
}

__global__ __launch_bounds__(256, 2)
void gate_kernel(const float* __restrict__ x, const float* __restrict__ w,
                 const float* __restrict__ b, float* __restrict__ out,
                 float* __restrict__ denom)
{
    __shared__ float lds[2 * BUFF];   // 64 KB -> 2 blocks/CU

    const int tid  = threadIdx.x;
    const int lane = tid & 63;
    const int wv   = tid >> 6;
    const int tok0 = blockIdx.x * TB;

    // stage chunk c (W: 16KB contiguous; x: 64 token-rows x 256B) into buf
    auto stage = [&](int buf, int c) {
        float* base = lds + buf * BUFF;
        const float* wsrc = w + (size_t)c * (DC * NEXP);
#pragma unroll
        for (int i = 0; i < 4; ++i) {
            const int off = (wv * 4 + i) * 256 + lane * 4;   // floats; linear in lane
            GLDS16(wsrc + off, base + WOFF + off);
        }
        const float* xsrc = x + (size_t)tok0 * DIM + c * DC;
#pragma unroll
        for (int i = 0; i < 4; ++i) {
            const int tg = wv * 16 + i * 4 + (lane >> 4);    // token in block
            // LDS offset = tg*64 + (lane&15)*4 = base' + lane*4 -> linear in lane
            GLDS16(xsrc + (size_t)tg * DIM + (lane & 15) * 4,
                   base + XOFF + tg * DC + (lane & 15) * 4);
        }
    };

    float acc[TPW], cmp[TPW];
#pragma unroll
    for (int j = 0; j < TPW; ++j) { acc[j] = 0.0f; cmp[j] = 0.0f; }

    stage(0, 0);

    for (int c = 0; c < NC; ++c) {
        const int cur = c & 1;
        __syncthreads();   // vmcnt(0)+barrier: buf[cur] ready; buf[cur^1] reads all done
        if (c + 1 < NC) stage(cur ^ 1, c + 1);

        const float* wbuf = lds + cur * BUFF + WOFF;
        const float* xbuf = lds + cur * BUFF + XOFF + (wv * TPW) * DC;

        float ca[TPW];
#pragma unroll
        for (int j = 0; j < TPW; ++j) ca[j] = 0.0f;

#pragma unroll 2
        for (int d4 = 0; d4 < DC; d4 += 4) {
            // W: lane-consecutive floats -> 2-way bank alias (free)
            const float w0 = wbuf[(d4 + 0) * NEXP + lane];
            const float w1 = wbuf[(d4 + 1) * NEXP + lane];
            const float w2 = wbuf[(d4 + 2) * NEXP + lane];
            const float w3 = wbuf[(d4 + 3) * NEXP + lane];
#pragma unroll
            for (int j = 0; j < TPW; ++j) {
                // x: wave-uniform address -> broadcast, conflict-free
                const float4 xv = *(const float4*)&xbuf[j * DC + d4];
                float a = ca[j];
                a = fmaf(xv.x, w0, a);
                a = fmaf(xv.y, w1, a);
                a = fmaf(xv.z, w2, a);
                a = fmaf(xv.w, w3, a);
                ca[j] = a;
            }
        }
        // Kahan fold (protects argmax vs np fp32 reference)
#pragma unroll
        for (int j = 0; j < TPW; ++j) {
            float y = ca[j] - cmp[j];
            float t = acc[j] + y;
            cmp[j] = (t - acc[j]) - y;
            acc[j] = t;
        }
    }

    // reuse dead buf0 W region for per-block denom aggregation
    __syncthreads();
    if (tid < NEXP) lds[tid] = 0.0f;
    __syncthreads();

    const float bias = b[lane];
#pragma unroll
    for (int j = 0; j < TPW; ++j) {
        const float v = acc[j] + bias;

        // wave argmax, FIRST index on ties (matches jnp.argmax)
        float m = v; int mi = lane;
#pragma unroll
        for (int off = 32; off > 0; off >>= 1) {
            float om = __shfl_xor(m, off);
            int   oi = __shfl_xor(mi, off);
            if (om > m || (om == m && oi < mi)) { m = om; mi = oi; }
        }
        float s = __expf(v - m);
#pragma unroll
        for (int off = 32; off > 0; off >>= 1) s += __shfl_xor(s, off);
        const float g = 1.0f / s;   // top-1 gate = exp(0)/sum

        const int t = tok0 + wv * TPW + j;
        out[(size_t)t * NEXP + lane] = (lane == mi) ? g : 0.0f;
        if (lane == mi) atomicAdd(&lds[mi], g);
    }

    __syncthreads();
    if (tid < NEXP) atomicAdd(&denom[tid], lds[tid]);
}

// out[n,e] *= capacity / (denom[e] + eps); zeros stay zero (branch-free)
__global__ __launch_bounds__(256)
void scale_kernel(float* __restrict__ out, const float* __restrict__ denom)
{
    __shared__ float sc[NEXP];
    if (threadIdx.x < NEXP)
        sc[threadIdx.x] = (float)NTOK / (denom[threadIdx.x] + 1e-6f);
    __syncthreads();

    const size_t i = (size_t)blockIdx.x * blockDim.x + threadIdx.x; // float4 idx
    float4 v = ((const float4*)out)[i];
    const int e0 = (int)((i * 4) & (NEXP - 1));
    v.x *= sc[e0]; v.y *= sc[e0 + 1]; v.z *= sc[e0 + 2]; v.w *= sc[e0 + 3];
    ((float4*)out)[i] = v;
}

extern "C" void kernel_launch(void* const* d_in, const int* in_sizes, int n_in,
                              void* d_out, int out_size, void* d_ws, size_t ws_size,
                              hipStream_t stream) {
    const float* x = (const float*)d_in[0];
    const float* w = (const float*)d_in[1];
    const float* b = (const float*)d_in[2];
    float* out   = (float*)d_out;
    float* denom = (float*)d_ws;   // 64 floats

    zero_denom_kernel<<<1, NEXP, 0, stream>>>(denom);
    gate_kernel<<<NBLK, 256, 0, stream>>>(x, w, b, out, denom);
    scale_kernel<<<(NTOK * NEXP / 4) / 256, 256, 0, stream>>>(out, denom);
}